// Round 1
// baseline (683.120 us; speedup 1.0000x reference)
//
#include <hip/hip_runtime.h>
#include <hip/hip_bf16.h>

typedef unsigned short u16;
typedef float f32x4 __attribute__((ext_vector_type(4)));
typedef __bf16 bf16x8 __attribute__((ext_vector_type(8)));

constexpr int TSEQ = 4096;   // sequence length
constexpr int DMOD = 4096;   // d_model
constexpr int HID  = 2048;   // d_hidden
constexpr int HID2 = 4096;   // 2*HID (re/im planes)
constexpr int NCH  = 64;     // scan chunks
constexpr int CHL  = 64;     // chunk length (NCH*CHL == TSEQ)

// ---------- helpers ----------
__device__ __forceinline__ u16 f2bf(float f) {
  unsigned u = __builtin_bit_cast(unsigned, f);
  u += 0x7fffu + ((u >> 16) & 1u);   // RNE
  return (u16)(u >> 16);
}
__device__ __forceinline__ unsigned pack2(float a, float b) {
  return (unsigned)f2bf(a) | ((unsigned)f2bf(b) << 16);
}
__device__ __forceinline__ void load_lds16(const u16* g, u16* l) {
  __builtin_amdgcn_global_load_lds((const __attribute__((address_space(1))) void*)g,
                                   (__attribute__((address_space(3))) void*)l,
                                   16, 0, 0);
}

// ---------- prep kernels ----------
__global__ __launch_bounds__(256) void k_lambda(const float* __restrict__ nu_log,
                                                const float* __restrict__ theta_log,
                                                float* __restrict__ lam_re, float* __restrict__ lam_im,
                                                float* __restrict__ lamL_re, float* __restrict__ lamL_im) {
  int h = blockIdx.x * 256 + threadIdx.x;
  if (h >= HID) return;
  float nu = expf(nu_log[h]);
  float th = expf(theta_log[h]);
  float mag = expf(-nu);
  float lr = mag * cosf(th), li = mag * sinf(th);
  lam_re[h] = lr; lam_im[h] = li;
  float pr = lr, pi = li;
#pragma unroll
  for (int i = 0; i < 6; ++i) {   // lam^64 via 6 squarings
    float nr = pr * pr - pi * pi;
    float ni = 2.f * pr * pi;
    pr = nr; pi = ni;
  }
  lamL_re[h] = pr; lamL_im[h] = pi;
}

__global__ __launch_bounds__(256) void k_cast_x(const float* __restrict__ x, u16* __restrict__ xb) {
  size_t i = ((size_t)blockIdx.x * 256 + threadIdx.x) * 4;
  float4 v = *reinterpret_cast<const float4*>(x + i);
  uint2 o;
  o.x = pack2(v.x, v.y);
  o.y = pack2(v.z, v.w);
  *reinterpret_cast<uint2*>(xb + i) = o;
}

// Bcat (2H x D) bf16: rows [0,H) = B_re*gamma, rows [H,2H) = B_im*gamma
__global__ __launch_bounds__(256) void k_make_bcat(const float* __restrict__ Bre, const float* __restrict__ Bim,
                                                   const float* __restrict__ gamma_log, u16* __restrict__ Bcat) {
  int idx = blockIdx.x * 256 + threadIdx.x;      // HID*DMOD/4 threads
  int h  = idx / (DMOD / 4);
  int dv = (idx % (DMOD / 4)) * 4;
  float g = expf(gamma_log[h]);
  float4 r  = *reinterpret_cast<const float4*>(Bre + (size_t)h * DMOD + dv);
  float4 im = *reinterpret_cast<const float4*>(Bim + (size_t)h * DMOD + dv);
  uint2 orr; orr.x = pack2(r.x * g, r.y * g); orr.y = pack2(r.z * g, r.w * g);
  *reinterpret_cast<uint2*>(Bcat + (size_t)h * DMOD + dv) = orr;
  uint2 oim; oim.x = pack2(im.x * g, im.y * g); oim.y = pack2(im.z * g, im.w * g);
  *reinterpret_cast<uint2*>(Bcat + (size_t)(h + HID) * DMOD + dv) = oim;
}

// Ccat (D x 2H) bf16: cols [0,H) = C_re, cols [H,2H) = -C_im
__global__ __launch_bounds__(256) void k_make_ccat(const float* __restrict__ Cre, const float* __restrict__ Cim,
                                                   u16* __restrict__ Ccat) {
  int idx = blockIdx.x * 256 + threadIdx.x;      // DMOD*HID/4 threads
  int d  = idx / (HID / 4);
  int hv = (idx % (HID / 4)) * 4;
  float4 r  = *reinterpret_cast<const float4*>(Cre + (size_t)d * HID + hv);
  float4 im = *reinterpret_cast<const float4*>(Cim + (size_t)d * HID + hv);
  uint2 orr; orr.x = pack2(r.x, r.y); orr.y = pack2(r.z, r.w);
  *reinterpret_cast<uint2*>(Ccat + (size_t)d * HID2 + hv) = orr;
  uint2 oim; oim.x = pack2(-im.x, -im.y); oim.y = pack2(-im.z, -im.w);
  *reinterpret_cast<uint2*>(Ccat + (size_t)d * HID2 + HID + hv) = oim;
}

// ---------- GEMM: C(MxN) = A(MxK) @ Bt(NxK)^T, bf16 MFMA, fp32 out ----------
// m97-structure: 128x128 tile, BK=32, 4 waves (2x2), global_load_lds width 16.
template <bool EPI>
__global__ __launch_bounds__(256) void gemm_bt(const u16* __restrict__ A, const u16* __restrict__ Bt,
                                               float* __restrict__ C, int M, int N, int K,
                                               const float* __restrict__ resid,
                                               const float* __restrict__ dvec) {
  __shared__ __align__(16) u16 As[128 * 32];
  __shared__ __align__(16) u16 Bs[128 * 32];

  int nbx = N >> 7;
  int nwg = gridDim.x;
  int wg = blockIdx.x;
  if ((nwg & 7) == 0) wg = (wg & 7) * (nwg >> 3) + (wg >> 3);   // XCD swizzle (bijective: nwg%8==0)
  int bm = (wg / nbx) << 7;
  int bn = (wg % nbx) << 7;

  int tid  = threadIdx.x;
  int lane = tid & 63;
  int wave = tid >> 6;
  int wr = (wave >> 1) * 64;   // wave's 64x64 sub-tile
  int wc = (wave & 1) * 64;

  f32x4 acc[4][4] = {};

  // staging: each wave issues 2 A-loads + 2 B-loads of 1024B (16 rows x 64B)
  int arow0 = wave * 32 + (lane >> 2);       // + 0 / +16 for the two issues
  int acol  = (lane & 3) * 8;
  const u16* gA = A  + (size_t)(bm + arow0) * K + acol;
  const u16* gB = Bt + (size_t)(bn + arow0) * K + acol;
  u16* lA = As + wave * 1024;
  u16* lB = Bs + wave * 1024;

  int lr = lane & 15;
  int lk = (lane >> 4) * 8;

  for (int k0 = 0; k0 < K; k0 += 32) {
    load_lds16(gA,                lA);
    load_lds16(gA + (size_t)16*K, lA + 512);
    load_lds16(gB,                lB);
    load_lds16(gB + (size_t)16*K, lB + 512);
    gA += 32; gB += 32;
    __syncthreads();   // compiler drains vmcnt before barrier -> staged data visible

    bf16x8 af[4], bfr[4];
#pragma unroll
    for (int m = 0; m < 4; ++m)
      af[m] = *reinterpret_cast<const bf16x8*>(&As[(wr + m * 16 + lr) * 32 + lk]);
#pragma unroll
    for (int n = 0; n < 4; ++n)
      bfr[n] = *reinterpret_cast<const bf16x8*>(&Bs[(wc + n * 16 + lr) * 32 + lk]);
#pragma unroll
    for (int m = 0; m < 4; ++m)
#pragma unroll
      for (int n = 0; n < 4; ++n)
        acc[m][n] = __builtin_amdgcn_mfma_f32_16x16x32_bf16(af[m], bfr[n], acc[m][n], 0, 0, 0);
    __syncthreads();
  }

  // epilogue: C/D mapping col = lane&15, row = (lane>>4)*4 + j  [verified m89/m91]
  int crow0 = bm + wr + ((lane >> 4) << 2);
  int ccol0 = bn + wc + (lane & 15);
#pragma unroll
  for (int m = 0; m < 4; ++m) {
#pragma unroll
    for (int n = 0; n < 4; ++n) {
#pragma unroll
      for (int j = 0; j < 4; ++j) {
        int row = crow0 + m * 16 + j;
        int col = ccol0 + n * 16;
        float v = acc[m][n][j];
        if constexpr (EPI) v += resid[(size_t)row * N + col] * dvec[col];
        C[(size_t)row * N + col] = v;
      }
    }
  }
}

// ---------- chunked scan over T ----------
// Bu layout: (T x 2H) fp32, col h = re, col H+h = im (lives in d_out between G1 and G2)
__global__ __launch_bounds__(256) void s_chunk_end(const float* __restrict__ Bu,
                                                   const float* __restrict__ lam_re,
                                                   const float* __restrict__ lam_im,
                                                   float* __restrict__ E) {
  int t = blockIdx.x * 256 + threadIdx.x;   // NCH*HID threads
  int h = t & (HID - 1);
  int c = t >> 11;
  float lr = lam_re[h], li = lam_im[h];
  float sr = 0.f, si = 0.f;
  const float* base = Bu + (size_t)c * CHL * HID2;
#pragma unroll 4
  for (int i = 0; i < CHL; ++i) {
    float br = base[(size_t)i * HID2 + h];
    float bi = base[(size_t)i * HID2 + HID + h];
    float nr = lr * sr - li * si + br;
    float ni = lr * si + li * sr + bi;
    sr = nr; si = ni;
  }
  E[(size_t)c * HID + h] = sr;
  E[(size_t)NCH * HID + (size_t)c * HID + h] = si;
}

__global__ __launch_bounds__(256) void s_prefix(const float* __restrict__ lamL_re,
                                                const float* __restrict__ lamL_im,
                                                const float* __restrict__ E,
                                                float* __restrict__ P) {
  int h = blockIdx.x * 256 + threadIdx.x;
  if (h >= HID) return;
  float plr = lamL_re[h], pli = lamL_im[h];
  float pr = 0.f, pi = 0.f;
  for (int c = 0; c < NCH; ++c) {
    P[(size_t)c * HID + h] = pr;
    P[(size_t)NCH * HID + (size_t)c * HID + h] = pi;
    float er = E[(size_t)c * HID + h];
    float ei = E[(size_t)NCH * HID + (size_t)c * HID + h];
    float nr = plr * pr - pli * pi + er;
    float ni = plr * pi + pli * pr + ei;
    pr = nr; pi = ni;
  }
}

__global__ __launch_bounds__(256) void s_expand(const float* __restrict__ Bu,
                                                const float* __restrict__ lam_re,
                                                const float* __restrict__ lam_im,
                                                const float* __restrict__ P,
                                                u16* __restrict__ A2) {
  int t = blockIdx.x * 256 + threadIdx.x;
  int h = t & (HID - 1);
  int c = t >> 11;
  float lr = lam_re[h], li = lam_im[h];
  float sr = P[(size_t)c * HID + h];
  float si = P[(size_t)NCH * HID + (size_t)c * HID + h];
  const float* base = Bu + (size_t)c * CHL * HID2;
  u16* ob = A2 + (size_t)c * CHL * HID2;
#pragma unroll 4
  for (int i = 0; i < CHL; ++i) {
    float br = base[(size_t)i * HID2 + h];
    float bi = base[(size_t)i * HID2 + HID + h];
    float nr = lr * sr - li * si + br;
    float ni = lr * si + li * sr + bi;
    sr = nr; si = ni;
    ob[(size_t)i * HID2 + h]       = f2bf(sr);
    ob[(size_t)i * HID2 + HID + h] = f2bf(si);
  }
}

// ---------- launch ----------
extern "C" void kernel_launch(void* const* d_in, const int* in_sizes, int n_in,
                              void* d_out, int out_size, void* d_ws, size_t ws_size,
                              hipStream_t stream) {
  const float* inputs    = (const float*)d_in[0];
  const float* nu_log    = (const float*)d_in[1];
  const float* theta_log = (const float*)d_in[2];
  const float* gamma_log = (const float*)d_in[3];
  const float* B_re      = (const float*)d_in[4];
  const float* B_im      = (const float*)d_in[5];
  const float* C_re      = (const float*)d_in[6];
  const float* C_im      = (const float*)d_in[7];
  const float* Dvec      = (const float*)d_in[8];

  char* w = (char*)d_ws;
  u16* xb     = (u16*)w;                              // 33.5 MB; reused as hidden (A2) after G1
  u16* Bcat   = (u16*)(w + (size_t)33554432);         // 33.5 MB; reused as Ccat after G1
  float* lam_re  = (float*)(w + (size_t)67108864);
  float* lam_im  = lam_re + HID;
  float* lamL_re = lam_im + HID;
  float* lamL_im = lamL_re + HID;
  float* E       = lamL_im + HID;                     // NCH*HID*2 floats = 1 MB
  float* P       = E + (size_t)NCH * HID * 2;         // 1 MB

  float* Bu  = (float*)d_out;    // (T x 2H) fp32 == 67 MB == out buffer, dead before G2 writes
  float* out = (float*)d_out;

  k_lambda<<<dim3(HID / 256), dim3(256), 0, stream>>>(nu_log, theta_log, lam_re, lam_im, lamL_re, lamL_im);
  k_cast_x<<<dim3((TSEQ * DMOD / 4) / 256), dim3(256), 0, stream>>>(inputs, xb);
  k_make_bcat<<<dim3((HID * DMOD / 4) / 256), dim3(256), 0, stream>>>(B_re, B_im, gamma_log, Bcat);

  gemm_bt<false><<<dim3((TSEQ / 128) * (HID2 / 128)), dim3(256), 0, stream>>>(
      xb, Bcat, Bu, TSEQ, HID2, DMOD, nullptr, nullptr);

  s_chunk_end<<<dim3(NCH * HID / 256), dim3(256), 0, stream>>>(Bu, lam_re, lam_im, E);
  s_prefix<<<dim3(HID / 256), dim3(256), 0, stream>>>(lamL_re, lamL_im, E, P);
  s_expand<<<dim3(NCH * HID / 256), dim3(256), 0, stream>>>(Bu, lam_re, lam_im, P, xb /*A2*/);

  k_make_ccat<<<dim3((DMOD * HID / 4) / 256), dim3(256), 0, stream>>>(C_re, C_im, Bcat /*Ccat*/);

  gemm_bt<true><<<dim3((TSEQ / 128) * (DMOD / 128)), dim3(256), 0, stream>>>(
      xb /*hidden*/, Bcat /*Ccat*/, out, TSEQ, DMOD, HID2, inputs, Dvec);
}

// Round 2
// 480.618 us; speedup vs baseline: 1.4213x; 1.4213x over previous
//
#include <hip/hip_runtime.h>
#include <hip/hip_bf16.h>

typedef unsigned short u16;
typedef float f32x4 __attribute__((ext_vector_type(4)));
typedef __bf16 bf16x8 __attribute__((ext_vector_type(8)));

constexpr int TSEQ = 4096;   // sequence length
constexpr int DMOD = 4096;   // d_model
constexpr int HID  = 2048;   // d_hidden
constexpr int HID2 = 4096;   // 2*HID (re/im planes)
constexpr int NCH  = 64;     // scan chunks
constexpr int CHL  = 64;     // chunk length

// ---------- helpers ----------
__device__ __forceinline__ u16 f2bf(float f) {
  unsigned u = __builtin_bit_cast(unsigned, f);
  u += 0x7fffu + ((u >> 16) & 1u);   // RNE
  return (u16)(u >> 16);
}
__device__ __forceinline__ unsigned pack2(float a, float b) {
  return (unsigned)f2bf(a) | ((unsigned)f2bf(b) << 16);
}
__device__ __forceinline__ void load_lds16(const u16* g, u16* l) {
  __builtin_amdgcn_global_load_lds((const __attribute__((address_space(1))) void*)g,
                                   (__attribute__((address_space(3))) void*)l,
                                   16, 0, 0);
}
__device__ __forceinline__ unsigned lds_addr(const u16* p) {
  return (unsigned)(uintptr_t)(const __attribute__((address_space(3))) u16*)p;
}

// ---------- prep kernels ----------
__global__ __launch_bounds__(256) void k_lambda(const float* __restrict__ nu_log,
                                                const float* __restrict__ theta_log,
                                                float* __restrict__ lam_re, float* __restrict__ lam_im,
                                                float* __restrict__ lamL_re, float* __restrict__ lamL_im) {
  int h = blockIdx.x * 256 + threadIdx.x;
  if (h >= HID) return;
  float nu = expf(nu_log[h]);
  float th = expf(theta_log[h]);
  float mag = expf(-nu);
  float lr = mag * cosf(th), li = mag * sinf(th);
  lam_re[h] = lr; lam_im[h] = li;
  float pr = lr, pi = li;
#pragma unroll
  for (int i = 0; i < 6; ++i) {   // lam^64 via 6 squarings
    float nr = pr * pr - pi * pi;
    float ni = 2.f * pr * pi;
    pr = nr; pi = ni;
  }
  lamL_re[h] = pr; lamL_im[h] = pi;
}

__global__ __launch_bounds__(256) void k_cast_x(const float* __restrict__ x, u16* __restrict__ xb) {
  size_t i = ((size_t)blockIdx.x * 256 + threadIdx.x) * 4;
  float4 v = *reinterpret_cast<const float4*>(x + i);
  uint2 o;
  o.x = pack2(v.x, v.y);
  o.y = pack2(v.z, v.w);
  *reinterpret_cast<uint2*>(xb + i) = o;
}

__global__ __launch_bounds__(256) void k_make_bcat(const float* __restrict__ Bre, const float* __restrict__ Bim,
                                                   const float* __restrict__ gamma_log, u16* __restrict__ Bcat) {
  int idx = blockIdx.x * 256 + threadIdx.x;
  int h  = idx / (DMOD / 4);
  int dv = (idx % (DMOD / 4)) * 4;
  float g = expf(gamma_log[h]);
  float4 r  = *reinterpret_cast<const float4*>(Bre + (size_t)h * DMOD + dv);
  float4 im = *reinterpret_cast<const float4*>(Bim + (size_t)h * DMOD + dv);
  uint2 orr; orr.x = pack2(r.x * g, r.y * g); orr.y = pack2(r.z * g, r.w * g);
  *reinterpret_cast<uint2*>(Bcat + (size_t)h * DMOD + dv) = orr;
  uint2 oim; oim.x = pack2(im.x * g, im.y * g); oim.y = pack2(im.z * g, im.w * g);
  *reinterpret_cast<uint2*>(Bcat + (size_t)(h + HID) * DMOD + dv) = oim;
}

__global__ __launch_bounds__(256) void k_make_ccat(const float* __restrict__ Cre, const float* __restrict__ Cim,
                                                   u16* __restrict__ Ccat) {
  int idx = blockIdx.x * 256 + threadIdx.x;
  int d  = idx / (HID / 4);
  int hv = (idx % (HID / 4)) * 4;
  float4 r  = *reinterpret_cast<const float4*>(Cre + (size_t)d * HID + hv);
  float4 im = *reinterpret_cast<const float4*>(Cim + (size_t)d * HID + hv);
  uint2 orr; orr.x = pack2(r.x, r.y); orr.y = pack2(r.z, r.w);
  *reinterpret_cast<uint2*>(Ccat + (size_t)d * HID2 + hv) = orr;
  uint2 oim; oim.x = pack2(-im.x, -im.y); oim.y = pack2(-im.z, -im.w);
  *reinterpret_cast<uint2*>(Ccat + (size_t)d * HID2 + HID + hv) = oim;
}

// ---------- 256^2 8-phase GEMM: C(4096x4096) = A(4096x4096) @ Bt(4096x4096)^T ----------
// 8 waves (2M x 4N), BK=64, 128 KiB LDS double-buffer, st-swizzled LDS, counted vmcnt.
#define DSR(d, a, IMM) asm volatile("ds_read_b128 %0, %1 offset:" IMM : "=v"(d) : "v"(a))

#define RD_A(B, O0, O1, O2, O3) do { \
  DSR(af[0][0], aAk0[B], O0); DSR(af[0][1], aAk1[B], O0); \
  DSR(af[1][0], aAk0[B], O1); DSR(af[1][1], aAk1[B], O1); \
  DSR(af[2][0], aAk0[B], O2); DSR(af[2][1], aAk1[B], O2); \
  DSR(af[3][0], aAk0[B], O3); DSR(af[3][1], aAk1[B], O3); } while (0)

#define RD_B(B, DST, O0, O1) do { \
  DSR(DST[0][0], aBk0[B], O0); DSR(DST[0][1], aBk1[B], O0); \
  DSR(DST[1][0], aBk0[B], O1); DSR(DST[1][1], aBk1[B], O1); } while (0)

#define STAGE_A(b, h, kb) do { const u16* _s = stA + (size_t)(h) * 128 * 4096 + (kb); \
  load_lds16(_s, dA[b][h]); load_lds16(_s + 64 * 4096, dA[b][h] + 4096); } while (0)
#define STAGE_B(b, h, kb) do { const u16* _s = stB + (size_t)(h) * 128 * 4096 + (kb); \
  load_lds16(_s, dB[b][h]); load_lds16(_s + 64 * 4096, dB[b][h] + 4096); } while (0)

#define MMQ(MB, NB, BF) do { \
  _Pragma("unroll") for (int m = 0; m < 4; ++m) { \
  _Pragma("unroll") for (int n = 0; n < 2; ++n) { \
    acc[(MB)+m][(NB)+n] = __builtin_amdgcn_mfma_f32_16x16x32_bf16(af[m][0], BF[n][0], acc[(MB)+m][(NB)+n], 0, 0, 0); \
    acc[(MB)+m][(NB)+n] = __builtin_amdgcn_mfma_f32_16x16x32_bf16(af[m][1], BF[n][1], acc[(MB)+m][(NB)+n], 0, 0, 0); } } } while (0)

#define MID() do { __builtin_amdgcn_s_barrier(); \
  asm volatile("s_waitcnt lgkmcnt(0)"); \
  __builtin_amdgcn_sched_barrier(0); \
  __builtin_amdgcn_s_setprio(1); } while (0)
#define ENDP() do { __builtin_amdgcn_s_setprio(0); \
  __builtin_amdgcn_s_barrier(); } while (0)
#define ENDPV() do { __builtin_amdgcn_s_setprio(0); \
  asm volatile("s_waitcnt vmcnt(4)"); \
  __builtin_amdgcn_s_barrier(); } while (0)

template <bool EPI>
__global__ __launch_bounds__(512, 2) void gemm8(const u16* __restrict__ A, const u16* __restrict__ Bt,
                                                float* __restrict__ C,
                                                const float* __restrict__ resid,
                                                const float* __restrict__ dvec) {
  constexpr int K = 4096, N = 4096;
  constexpr int NI = (K / 64) / 2;   // 32 iterations, 2 K-tiles each
  __shared__ __align__(16) u16 L[65536];   // 128 KiB

  int nwg = gridDim.x;                       // 256 (16x16), %8==0
  int wg = blockIdx.x;
  wg = (wg & 7) * (nwg >> 3) + (wg >> 3);    // XCD-chunked swizzle (bijective)
  int bm = (wg >> 4) << 8;
  int bn = (wg & 15) << 8;

  int tid = threadIdx.x;
  int lane = tid & 63;
  int wave = tid >> 6;
  int wm = wave >> 2, wn = wave & 3;
  int l15 = lane & 15, g = lane >> 4;

  // ds_read addresses (swizzle: byte ^= (row&7)<<4; row&7 == l15&7 for all frags)
  unsigned offk0 = (unsigned)(((unsigned)g << 4) ^ ((unsigned)(lane & 7) << 4));
  unsigned offk1 = offk0 ^ 64u;
  unsigned aAk0[2], aAk1[2], aBk0[2], aBk1[2];
#pragma unroll
  for (int b = 0; b < 2; ++b) {
    unsigned ab = lds_addr(&L[b * 32768 + wm * 8192 + l15 * 64]);
    aAk0[b] = ab + offk0; aAk1[b] = ab + offk1;
    unsigned bb = lds_addr(&L[b * 32768 + 16384 + (wn >> 1) * 8192 + (wn & 1) * 4096 + l15 * 64]);
    aBk0[b] = bb + offk0; aBk1[b] = bb + offk1;
  }

  // staging: thread tid covers (row = q*64 + tid>>3, chunk = tid&7), source pre-unswizzled
  int trow = tid >> 3;
  int tchk = ((tid & 7) ^ (trow & 7)) << 3;   // element offset within 64-col K-tile
  const u16* stA = A  + (size_t)(bm + trow) * K + tchk;
  const u16* stB = Bt + (size_t)(bn + trow) * K + tchk;
  u16* dA[2][2]; u16* dB[2][2];
#pragma unroll
  for (int b = 0; b < 2; ++b)
#pragma unroll
    for (int h = 0; h < 2; ++h) {
      dA[b][h] = &L[b * 32768 + h * 8192 + tid * 8];
      dB[b][h] = &L[b * 32768 + 16384 + h * 8192 + tid * 8];
    }

  bf16x8 af[4][2], b0[2][2], b1[2][2];
  f32x4 acc[8][4];
#pragma unroll
  for (int i = 0; i < 8; ++i)
#pragma unroll
    for (int n = 0; n < 4; ++n) acc[i][n] = (f32x4){0.f, 0.f, 0.f, 0.f};

  // prologue: tile0 -> buf0 (all 4 halves), tile1 -> buf1 (Bh0, Ah0)
  STAGE_B(0, 0, 0);  STAGE_A(0, 0, 0);
  STAGE_B(0, 1, 0);  STAGE_A(0, 1, 0);
  STAGE_B(1, 0, 64); STAGE_A(1, 0, 64);
  asm volatile("s_waitcnt vmcnt(4)");   // buf0 fully landed; buf1's 2 stages may fly
  __builtin_amdgcn_s_barrier();

#pragma unroll 1
  for (int j = 0; j < NI; ++j) {
    int kb1 = ((2 * j + 1) << 6) & (K - 1);
    int kb2 = ((2 * j + 2) << 6) & (K - 1);
    int kb3 = ((2 * j + 3) << 6) & (K - 1);
    // ---- K-tile 2j (buf0) ----
    // P1: quad(0,0)
    RD_A(0, "0", "2048", "4096", "6144");
    RD_B(0, b0, "0", "2048");
    STAGE_B(1, 1, kb1);
    MID(); MMQ(0, 0, b0); ENDP();
    // P2: quad(0,1)
    RD_B(0, b1, "4096", "6144");
    STAGE_A(1, 1, kb1);
    MID(); MMQ(0, 2, b1); ENDP();
    // P3: quad(1,1)
    RD_A(0, "8192", "10240", "12288", "14336");
    STAGE_B(0, 0, kb2);
    MID(); MMQ(4, 2, b1); ENDP();
    // P4: quad(1,0)
    STAGE_A(0, 0, kb2);
    MID(); MMQ(4, 0, b0); ENDPV();
    // ---- K-tile 2j+1 (buf1) ----
    // P5
    RD_A(1, "0", "2048", "4096", "6144");
    RD_B(1, b0, "0", "2048");
    STAGE_B(0, 1, kb2);
    MID(); MMQ(0, 0, b0); ENDP();
    // P6
    RD_B(1, b1, "4096", "6144");
    STAGE_A(0, 1, kb2);
    MID(); MMQ(0, 2, b1); ENDP();
    // P7
    RD_A(1, "8192", "10240", "12288", "14336");
    STAGE_B(1, 0, kb3);
    MID(); MMQ(4, 2, b1); ENDP();
    // P8
    STAGE_A(1, 0, kb3);
    MID(); MMQ(4, 0, b0); ENDPV();
  }

  // epilogue: C/D mapping col = lane&15, row = (lane>>4)*4 + j
  int crow = bm + wm * 128 + (g << 2);
  int ccol = bn + wn * 64 + l15;
#pragma unroll
  for (int mi = 0; mi < 8; ++mi)
#pragma unroll
    for (int ni = 0; ni < 4; ++ni)
#pragma unroll
      for (int jj = 0; jj < 4; ++jj) {
        int row = crow + mi * 16 + jj;
        int col = ccol + ni * 16;
        float v = acc[mi][ni][jj];
        if constexpr (EPI) v += resid[(size_t)row * N + col] * dvec[col];
        C[(size_t)row * N + col] = v;
      }
}

// ---------- chunked scan over T ----------
__global__ __launch_bounds__(256) void s_chunk_end(const float* __restrict__ Bu,
                                                   const float* __restrict__ lam_re,
                                                   const float* __restrict__ lam_im,
                                                   float* __restrict__ E) {
  int t = blockIdx.x * 256 + threadIdx.x;
  int h = t & (HID - 1);
  int c = t >> 11;
  float lr = lam_re[h], li = lam_im[h];
  float sr = 0.f, si = 0.f;
  const float* base = Bu + (size_t)c * CHL * HID2;
#pragma unroll 4
  for (int i = 0; i < CHL; ++i) {
    float br = base[(size_t)i * HID2 + h];
    float bi = base[(size_t)i * HID2 + HID + h];
    float nr = lr * sr - li * si + br;
    float ni = lr * si + li * sr + bi;
    sr = nr; si = ni;
  }
  E[(size_t)c * HID + h] = sr;
  E[(size_t)NCH * HID + (size_t)c * HID + h] = si;
}

__global__ __launch_bounds__(256) void s_prefix(const float* __restrict__ lamL_re,
                                                const float* __restrict__ lamL_im,
                                                const float* __restrict__ E,
                                                float* __restrict__ P) {
  int h = blockIdx.x * 256 + threadIdx.x;
  if (h >= HID) return;
  float plr = lamL_re[h], pli = lamL_im[h];
  float pr = 0.f, pi = 0.f;
  for (int c = 0; c < NCH; ++c) {
    P[(size_t)c * HID + h] = pr;
    P[(size_t)NCH * HID + (size_t)c * HID + h] = pi;
    float er = E[(size_t)c * HID + h];
    float ei = E[(size_t)NCH * HID + (size_t)c * HID + h];
    float nr = plr * pr - pli * pi + er;
    float ni = plr * pi + pli * pr + ei;
    pr = nr; pi = ni;
  }
}

__global__ __launch_bounds__(256) void s_expand(const float* __restrict__ Bu,
                                                const float* __restrict__ lam_re,
                                                const float* __restrict__ lam_im,
                                                const float* __restrict__ P,
                                                u16* __restrict__ A2) {
  int t = blockIdx.x * 256 + threadIdx.x;
  int h = t & (HID - 1);
  int c = t >> 11;
  float lr = lam_re[h], li = lam_im[h];
  float sr = P[(size_t)c * HID + h];
  float si = P[(size_t)NCH * HID + (size_t)c * HID + h];
  const float* base = Bu + (size_t)c * CHL * HID2;
  u16* ob = A2 + (size_t)c * CHL * HID2;
#pragma unroll 4
  for (int i = 0; i < CHL; ++i) {
    float br = base[(size_t)i * HID2 + h];
    float bi = base[(size_t)i * HID2 + HID + h];
    float nr = lr * sr - li * si + br;
    float ni = lr * si + li * sr + bi;
    sr = nr; si = ni;
    ob[(size_t)i * HID2 + h]       = f2bf(sr);
    ob[(size_t)i * HID2 + HID + h] = f2bf(si);
  }
}

// ---------- launch ----------
extern "C" void kernel_launch(void* const* d_in, const int* in_sizes, int n_in,
                              void* d_out, int out_size, void* d_ws, size_t ws_size,
                              hipStream_t stream) {
  const float* inputs    = (const float*)d_in[0];
  const float* nu_log    = (const float*)d_in[1];
  const float* theta_log = (const float*)d_in[2];
  const float* gamma_log = (const float*)d_in[3];
  const float* B_re      = (const float*)d_in[4];
  const float* B_im      = (const float*)d_in[5];
  const float* C_re      = (const float*)d_in[6];
  const float* C_im      = (const float*)d_in[7];
  const float* Dvec      = (const float*)d_in[8];

  char* w = (char*)d_ws;
  u16* xb     = (u16*)w;                              // 33.5 MB; reused as hidden (A2) after G1
  u16* Bcat   = (u16*)(w + (size_t)33554432);         // 33.5 MB; reused as Ccat after G1
  float* lam_re  = (float*)(w + (size_t)67108864);
  float* lam_im  = lam_re + HID;
  float* lamL_re = lam_im + HID;
  float* lamL_im = lamL_re + HID;
  float* E       = lamL_im + HID;
  float* P       = E + (size_t)NCH * HID * 2;

  float* Bu  = (float*)d_out;    // (T x 2H) fp32, dead before G2 writes
  float* out = (float*)d_out;

  k_lambda<<<dim3(HID / 256), dim3(256), 0, stream>>>(nu_log, theta_log, lam_re, lam_im, lamL_re, lamL_im);
  k_cast_x<<<dim3((TSEQ * DMOD / 4) / 256), dim3(256), 0, stream>>>(inputs, xb);
  k_make_bcat<<<dim3((HID * DMOD / 4) / 256), dim3(256), 0, stream>>>(B_re, B_im, gamma_log, Bcat);

  gemm8<false><<<dim3((TSEQ / 256) * (HID2 / 256)), dim3(512), 0, stream>>>(
      xb, Bcat, Bu, nullptr, nullptr);

  s_chunk_end<<<dim3(NCH * HID / 256), dim3(256), 0, stream>>>(Bu, lam_re, lam_im, E);
  s_prefix<<<dim3(HID / 256), dim3(256), 0, stream>>>(lamL_re, lamL_im, E, P);
  s_expand<<<dim3(NCH * HID / 256), dim3(256), 0, stream>>>(Bu, lam_re, lam_im, P, xb /*A2*/);

  k_make_ccat<<<dim3((DMOD * HID / 4) / 256), dim3(256), 0, stream>>>(C_re, C_im, Bcat /*Ccat*/);

  gemm8<true><<<dim3((TSEQ / 256) * (DMOD / 256)), dim3(512), 0, stream>>>(
      xb /*hidden*/, Bcat /*Ccat*/, out, inputs, Dvec);
}

// Round 3
// 478.843 us; speedup vs baseline: 1.4266x; 1.0037x over previous
//
#include <hip/hip_runtime.h>
#include <hip/hip_bf16.h>

typedef unsigned short u16;
typedef float f32x4 __attribute__((ext_vector_type(4)));
typedef __bf16 bf16x8 __attribute__((ext_vector_type(8)));

constexpr int TSEQ = 4096;   // sequence length
constexpr int DMOD = 4096;   // d_model
constexpr int HID  = 2048;   // d_hidden
constexpr int HID2 = 4096;   // 2*HID (re/im planes)
constexpr int NCH  = 64;     // scan chunks
constexpr int CHL  = 64;     // chunk length

// ---------- helpers ----------
__device__ __forceinline__ u16 f2bf(float f) {
  unsigned u = __builtin_bit_cast(unsigned, f);
  u += 0x7fffu + ((u >> 16) & 1u);   // RNE
  return (u16)(u >> 16);
}
__device__ __forceinline__ float bf2f(u16 u) {
  return __builtin_bit_cast(float, (unsigned)u << 16);
}
__device__ __forceinline__ unsigned pack2(float a, float b) {
  return (unsigned)f2bf(a) | ((unsigned)f2bf(b) << 16);
}
__device__ __forceinline__ void load_lds16(const u16* g, u16* l) {
  __builtin_amdgcn_global_load_lds((const __attribute__((address_space(1))) void*)g,
                                   (__attribute__((address_space(3))) void*)l,
                                   16, 0, 0);
}
__device__ __forceinline__ unsigned lds_addr(const u16* p) {
  return (unsigned)(uintptr_t)(const __attribute__((address_space(3))) u16*)p;
}

// ---------- prep kernels ----------
__global__ __launch_bounds__(256) void k_lambda(const float* __restrict__ nu_log,
                                                const float* __restrict__ theta_log,
                                                float* __restrict__ lam_re, float* __restrict__ lam_im,
                                                float* __restrict__ lamL_re, float* __restrict__ lamL_im) {
  int h = blockIdx.x * 256 + threadIdx.x;
  if (h >= HID) return;
  float nu = expf(nu_log[h]);
  float th = expf(theta_log[h]);
  float mag = expf(-nu);
  float lr = mag * cosf(th), li = mag * sinf(th);
  lam_re[h] = lr; lam_im[h] = li;
  float pr = lr, pi = li;
#pragma unroll
  for (int i = 0; i < 6; ++i) {   // lam^64 via 6 squarings
    float nr = pr * pr - pi * pi;
    float ni = 2.f * pr * pi;
    pr = nr; pi = ni;
  }
  lamL_re[h] = pr; lamL_im[h] = pi;
}

__global__ __launch_bounds__(256) void k_cast_x(const float* __restrict__ x, u16* __restrict__ xb) {
  size_t i = ((size_t)blockIdx.x * 256 + threadIdx.x) * 4;
  float4 v = *reinterpret_cast<const float4*>(x + i);
  uint2 o;
  o.x = pack2(v.x, v.y);
  o.y = pack2(v.z, v.w);
  *reinterpret_cast<uint2*>(xb + i) = o;
}

__global__ __launch_bounds__(256) void k_make_bcat(const float* __restrict__ Bre, const float* __restrict__ Bim,
                                                   const float* __restrict__ gamma_log, u16* __restrict__ Bcat) {
  int idx = blockIdx.x * 256 + threadIdx.x;
  int h  = idx / (DMOD / 4);
  int dv = (idx % (DMOD / 4)) * 4;
  float g = expf(gamma_log[h]);
  float4 r  = *reinterpret_cast<const float4*>(Bre + (size_t)h * DMOD + dv);
  float4 im = *reinterpret_cast<const float4*>(Bim + (size_t)h * DMOD + dv);
  uint2 orr; orr.x = pack2(r.x * g, r.y * g); orr.y = pack2(r.z * g, r.w * g);
  *reinterpret_cast<uint2*>(Bcat + (size_t)h * DMOD + dv) = orr;
  uint2 oim; oim.x = pack2(im.x * g, im.y * g); oim.y = pack2(im.z * g, im.w * g);
  *reinterpret_cast<uint2*>(Bcat + (size_t)(h + HID) * DMOD + dv) = oim;
}

__global__ __launch_bounds__(256) void k_make_ccat(const float* __restrict__ Cre, const float* __restrict__ Cim,
                                                   u16* __restrict__ Ccat) {
  int idx = blockIdx.x * 256 + threadIdx.x;
  int d  = idx / (HID / 4);
  int hv = (idx % (HID / 4)) * 4;
  float4 r  = *reinterpret_cast<const float4*>(Cre + (size_t)d * HID + hv);
  float4 im = *reinterpret_cast<const float4*>(Cim + (size_t)d * HID + hv);
  uint2 orr; orr.x = pack2(r.x, r.y); orr.y = pack2(r.z, r.w);
  *reinterpret_cast<uint2*>(Ccat + (size_t)d * HID2 + hv) = orr;
  uint2 oim; oim.x = pack2(-im.x, -im.y); oim.y = pack2(-im.z, -im.w);
  *reinterpret_cast<uint2*>(Ccat + (size_t)d * HID2 + HID + hv) = oim;
}

// ---------- 256^2 8-phase GEMM: C(4096x4096) = A(4096x4096) @ Bt(4096x4096)^T ----------
// 8 waves (2M x 4N), BK=64, 128 KiB LDS double-buffer, st-swizzled LDS, counted vmcnt.
#define DSR(d, a, IMM) asm volatile("ds_read_b128 %0, %1 offset:" IMM : "=v"(d) : "v"(a))

#define RD_A(B, O0, O1, O2, O3) do { \
  DSR(af[0][0], aAk0[B], O0); DSR(af[0][1], aAk1[B], O0); \
  DSR(af[1][0], aAk0[B], O1); DSR(af[1][1], aAk1[B], O1); \
  DSR(af[2][0], aAk0[B], O2); DSR(af[2][1], aAk1[B], O2); \
  DSR(af[3][0], aAk0[B], O3); DSR(af[3][1], aAk1[B], O3); } while (0)

#define RD_B(B, DST, O0, O1) do { \
  DSR(DST[0][0], aBk0[B], O0); DSR(DST[0][1], aBk1[B], O0); \
  DSR(DST[1][0], aBk0[B], O1); DSR(DST[1][1], aBk1[B], O1); } while (0)

#define STAGE_A(b, h, kb) do { const u16* _s = stA + (size_t)(h) * 128 * 4096 + (kb); \
  load_lds16(_s, dA[b][h]); load_lds16(_s + 64 * 4096, dA[b][h] + 4096); } while (0)
#define STAGE_B(b, h, kb) do { const u16* _s = stB + (size_t)(h) * 128 * 4096 + (kb); \
  load_lds16(_s, dB[b][h]); load_lds16(_s + 64 * 4096, dB[b][h] + 4096); } while (0)

// k-outer order: 8 independent (m,n) MFMAs at k0, then their k1 partners.
// Dependency distance 8 instructions -> matrix pipe stays at throughput.
#define MMQ(MB, NB, BF) do { \
  _Pragma("unroll") for (int k = 0; k < 2; ++k) { \
  _Pragma("unroll") for (int m = 0; m < 4; ++m) { \
  _Pragma("unroll") for (int n = 0; n < 2; ++n) { \
    acc[(MB)+m][(NB)+n] = __builtin_amdgcn_mfma_f32_16x16x32_bf16(af[m][k], BF[n][k], acc[(MB)+m][(NB)+n], 0, 0, 0); } } } } while (0)

#define MID() do { __builtin_amdgcn_s_barrier(); \
  asm volatile("s_waitcnt lgkmcnt(0)"); \
  __builtin_amdgcn_sched_barrier(0); \
  __builtin_amdgcn_s_setprio(1); } while (0)
#define ENDP() do { __builtin_amdgcn_s_setprio(0); \
  __builtin_amdgcn_s_barrier(); } while (0)
#define ENDPV() do { __builtin_amdgcn_s_setprio(0); \
  asm volatile("s_waitcnt vmcnt(4)"); \
  __builtin_amdgcn_s_barrier(); } while (0)

template <bool EPI>
__global__ __launch_bounds__(512, 2) void gemm8(const u16* __restrict__ A, const u16* __restrict__ Bt,
                                                void* __restrict__ Cout,
                                                const float* __restrict__ resid,
                                                const float* __restrict__ dvec) {
  constexpr int K = 4096, N = 4096;
  constexpr int NI = (K / 64) / 2;   // 32 iterations, 2 K-tiles each
  __shared__ __align__(16) u16 L[65536];   // 128 KiB

  int nwg = gridDim.x;                       // 256 (16x16), %8==0
  int wg = blockIdx.x;
  wg = (wg & 7) * (nwg >> 3) + (wg >> 3);    // XCD-chunked swizzle (bijective)
  int bm = (wg >> 4) << 8;
  int bn = (wg & 15) << 8;

  int tid = threadIdx.x;
  int lane = tid & 63;
  int wave = tid >> 6;
  int wm = wave >> 2, wn = wave & 3;
  int l15 = lane & 15, g = lane >> 4;

  // ds_read addresses (swizzle: byte ^= (row&7)<<4; row&7 == l15&7 for all frags)
  unsigned offk0 = (unsigned)(((unsigned)g << 4) ^ ((unsigned)(lane & 7) << 4));
  unsigned offk1 = offk0 ^ 64u;
  unsigned aAk0[2], aAk1[2], aBk0[2], aBk1[2];
#pragma unroll
  for (int b = 0; b < 2; ++b) {
    unsigned ab = lds_addr(&L[b * 32768 + wm * 8192 + l15 * 64]);
    aAk0[b] = ab + offk0; aAk1[b] = ab + offk1;
    unsigned bb = lds_addr(&L[b * 32768 + 16384 + (wn >> 1) * 8192 + (wn & 1) * 4096 + l15 * 64]);
    aBk0[b] = bb + offk0; aBk1[b] = bb + offk1;
  }

  // staging: thread tid covers (row = q*64 + tid>>3, chunk = tid&7), source pre-unswizzled
  int trow = tid >> 3;
  int tchk = ((tid & 7) ^ (trow & 7)) << 3;   // element offset within 64-col K-tile
  const u16* stA = A  + (size_t)(bm + trow) * K + tchk;
  const u16* stB = Bt + (size_t)(bn + trow) * K + tchk;
  u16* dA[2][2]; u16* dB[2][2];
#pragma unroll
  for (int b = 0; b < 2; ++b)
#pragma unroll
    for (int h = 0; h < 2; ++h) {
      dA[b][h] = &L[b * 32768 + h * 8192 + tid * 8];
      dB[b][h] = &L[b * 32768 + 16384 + h * 8192 + tid * 8];
    }

  bf16x8 af[4][2], b0[2][2], b1[2][2];
  f32x4 acc[8][4];
#pragma unroll
  for (int i = 0; i < 8; ++i)
#pragma unroll
    for (int n = 0; n < 4; ++n) acc[i][n] = (f32x4){0.f, 0.f, 0.f, 0.f};

  // prologue: tile0 -> buf0 (all 4 halves), tile1 -> buf1 (Bh0, Ah0)
  STAGE_B(0, 0, 0);  STAGE_A(0, 0, 0);
  STAGE_B(0, 1, 0);  STAGE_A(0, 1, 0);
  STAGE_B(1, 0, 64); STAGE_A(1, 0, 64);
  asm volatile("s_waitcnt vmcnt(4)");   // buf0 fully landed; buf1's 2 stages may fly
  __builtin_amdgcn_s_barrier();

#pragma unroll 1
  for (int j = 0; j < NI; ++j) {
    int kb1 = ((2 * j + 1) << 6) & (K - 1);
    int kb2 = ((2 * j + 2) << 6) & (K - 1);
    int kb3 = ((2 * j + 3) << 6) & (K - 1);
    // ---- K-tile 2j (buf0) ----
    // P1: quad(0,0)
    RD_A(0, "0", "2048", "4096", "6144");
    RD_B(0, b0, "0", "2048");
    STAGE_B(1, 1, kb1);
    MID(); MMQ(0, 0, b0); ENDP();
    // P2: quad(0,1)
    RD_B(0, b1, "4096", "6144");
    STAGE_A(1, 1, kb1);
    MID(); MMQ(0, 2, b1); ENDP();
    // P3: quad(1,1)
    RD_A(0, "8192", "10240", "12288", "14336");
    STAGE_B(0, 0, kb2);
    MID(); MMQ(4, 2, b1); ENDP();
    // P4: quad(1,0)
    STAGE_A(0, 0, kb2);
    MID(); MMQ(4, 0, b0); ENDPV();
    // ---- K-tile 2j+1 (buf1) ----
    // P5
    RD_A(1, "0", "2048", "4096", "6144");
    RD_B(1, b0, "0", "2048");
    STAGE_B(0, 1, kb2);
    MID(); MMQ(0, 0, b0); ENDP();
    // P6
    RD_B(1, b1, "4096", "6144");
    STAGE_A(0, 1, kb2);
    MID(); MMQ(0, 2, b1); ENDP();
    // P7
    RD_A(1, "8192", "10240", "12288", "14336");
    STAGE_B(1, 0, kb3);
    MID(); MMQ(4, 2, b1); ENDP();
    // P8
    STAGE_A(1, 0, kb3);
    MID(); MMQ(4, 0, b0); ENDPV();
  }

  // epilogue: C/D mapping col = lane&15, row = (lane>>4)*4 + j
  int crow = bm + wm * 128 + (g << 2);
  int ccol = bn + wn * 64 + l15;
#pragma unroll
  for (int mi = 0; mi < 8; ++mi)
#pragma unroll
    for (int ni = 0; ni < 4; ++ni)
#pragma unroll
      for (int jj = 0; jj < 4; ++jj) {
        int row = crow + mi * 16 + jj;
        int col = ccol + ni * 16;
        float v = acc[mi][ni][jj];
        if constexpr (EPI) {
          v += resid[(size_t)row * N + col] * dvec[col];
          ((float*)Cout)[(size_t)row * N + col] = v;
        } else {
          ((u16*)Cout)[(size_t)row * N + col] = f2bf(v);   // Bu in bf16
        }
      }
}

// ---------- chunked scan over T (Bu is bf16, 4 channels/thread) ----------
__global__ __launch_bounds__(256) void s_chunk_end(const u16* __restrict__ Bu,
                                                   const float* __restrict__ lam_re,
                                                   const float* __restrict__ lam_im,
                                                   float* __restrict__ E) {
  int t = blockIdx.x * 256 + threadIdx.x;     // NCH*HID/4 threads
  int hq = t & (HID / 4 - 1);
  int c  = t >> 9;
  int h0 = hq << 2;
  float4 lr = *reinterpret_cast<const float4*>(lam_re + h0);
  float4 li = *reinterpret_cast<const float4*>(lam_im + h0);
  float sr[4] = {0.f, 0.f, 0.f, 0.f}, si[4] = {0.f, 0.f, 0.f, 0.f};
  const float lrv[4] = {lr.x, lr.y, lr.z, lr.w};
  const float liv[4] = {li.x, li.y, li.z, li.w};
  const u16* base = Bu + (size_t)c * CHL * HID2 + h0;
#pragma unroll 8
  for (int i = 0; i < CHL; ++i) {
    ushort4 vre = *reinterpret_cast<const ushort4*>(base + (size_t)i * HID2);
    ushort4 vim = *reinterpret_cast<const ushort4*>(base + (size_t)i * HID2 + HID);
    float br[4] = {bf2f(vre.x), bf2f(vre.y), bf2f(vre.z), bf2f(vre.w)};
    float bi[4] = {bf2f(vim.x), bf2f(vim.y), bf2f(vim.z), bf2f(vim.w)};
#pragma unroll
    for (int q = 0; q < 4; ++q) {
      float nr = lrv[q] * sr[q] - liv[q] * si[q] + br[q];
      float ni = lrv[q] * si[q] + liv[q] * sr[q] + bi[q];
      sr[q] = nr; si[q] = ni;
    }
  }
  *reinterpret_cast<float4*>(E + (size_t)c * HID + h0) = (float4){sr[0], sr[1], sr[2], sr[3]};
  *reinterpret_cast<float4*>(E + (size_t)NCH * HID + (size_t)c * HID + h0) = (float4){si[0], si[1], si[2], si[3]};
}

__global__ __launch_bounds__(256) void s_prefix(const float* __restrict__ lamL_re,
                                                const float* __restrict__ lamL_im,
                                                const float* __restrict__ E,
                                                float* __restrict__ P) {
  int h = blockIdx.x * 256 + threadIdx.x;
  if (h >= HID) return;
  float plr = lamL_re[h], pli = lamL_im[h];
  float pr = 0.f, pi = 0.f;
#pragma unroll
  for (int c = 0; c < NCH; ++c) {
    P[(size_t)c * HID + h] = pr;
    P[(size_t)NCH * HID + (size_t)c * HID + h] = pi;
    float er = E[(size_t)c * HID + h];
    float ei = E[(size_t)NCH * HID + (size_t)c * HID + h];
    float nr = plr * pr - pli * pi + er;
    float ni = plr * pi + pli * pr + ei;
    pr = nr; pi = ni;
  }
}

__global__ __launch_bounds__(256) void s_expand(const u16* __restrict__ Bu,
                                                const float* __restrict__ lam_re,
                                                const float* __restrict__ lam_im,
                                                const float* __restrict__ P,
                                                u16* __restrict__ A2) {
  int t = blockIdx.x * 256 + threadIdx.x;
  int hq = t & (HID / 4 - 1);
  int c  = t >> 9;
  int h0 = hq << 2;
  float4 lr = *reinterpret_cast<const float4*>(lam_re + h0);
  float4 li = *reinterpret_cast<const float4*>(lam_im + h0);
  const float lrv[4] = {lr.x, lr.y, lr.z, lr.w};
  const float liv[4] = {li.x, li.y, li.z, li.w};
  float4 p0 = *reinterpret_cast<const float4*>(P + (size_t)c * HID + h0);
  float4 p1 = *reinterpret_cast<const float4*>(P + (size_t)NCH * HID + (size_t)c * HID + h0);
  float sr[4] = {p0.x, p0.y, p0.z, p0.w}, si[4] = {p1.x, p1.y, p1.z, p1.w};
  const u16* base = Bu + (size_t)c * CHL * HID2 + h0;
  u16* ob = A2 + (size_t)c * CHL * HID2 + h0;
#pragma unroll 8
  for (int i = 0; i < CHL; ++i) {
    ushort4 vre = *reinterpret_cast<const ushort4*>(base + (size_t)i * HID2);
    ushort4 vim = *reinterpret_cast<const ushort4*>(base + (size_t)i * HID2 + HID);
    float br[4] = {bf2f(vre.x), bf2f(vre.y), bf2f(vre.z), bf2f(vre.w)};
    float bi[4] = {bf2f(vim.x), bf2f(vim.y), bf2f(vim.z), bf2f(vim.w)};
#pragma unroll
    for (int q = 0; q < 4; ++q) {
      float nr = lrv[q] * sr[q] - liv[q] * si[q] + br[q];
      float ni = lrv[q] * si[q] + liv[q] * sr[q] + bi[q];
      sr[q] = nr; si[q] = ni;
    }
    ushort4 ore = {f2bf(sr[0]), f2bf(sr[1]), f2bf(sr[2]), f2bf(sr[3])};
    ushort4 oim = {f2bf(si[0]), f2bf(si[1]), f2bf(si[2]), f2bf(si[3])};
    *reinterpret_cast<ushort4*>(ob + (size_t)i * HID2) = ore;
    *reinterpret_cast<ushort4*>(ob + (size_t)i * HID2 + HID) = oim;
  }
}

// ---------- launch ----------
extern "C" void kernel_launch(void* const* d_in, const int* in_sizes, int n_in,
                              void* d_out, int out_size, void* d_ws, size_t ws_size,
                              hipStream_t stream) {
  const float* inputs    = (const float*)d_in[0];
  const float* nu_log    = (const float*)d_in[1];
  const float* theta_log = (const float*)d_in[2];
  const float* gamma_log = (const float*)d_in[3];
  const float* B_re      = (const float*)d_in[4];
  const float* B_im      = (const float*)d_in[5];
  const float* C_re      = (const float*)d_in[6];
  const float* C_im      = (const float*)d_in[7];
  const float* Dvec      = (const float*)d_in[8];

  char* w = (char*)d_ws;
  u16* xb     = (u16*)w;                              // 33.5 MB; reused as hidden (A2) after G1
  u16* Bcat   = (u16*)(w + (size_t)33554432);         // 33.5 MB; reused as Ccat after G1
  float* lam_re  = (float*)(w + (size_t)67108864);
  float* lam_im  = lam_re + HID;
  float* lamL_re = lam_im + HID;
  float* lamL_im = lamL_re + HID;
  float* E       = lamL_im + HID;
  float* P       = E + (size_t)NCH * HID * 2;

  u16* Bu    = (u16*)d_out;      // (T x 2H) bf16 (33.5 MB), dead before G2 writes
  float* out = (float*)d_out;

  k_lambda<<<dim3(HID / 256), dim3(256), 0, stream>>>(nu_log, theta_log, lam_re, lam_im, lamL_re, lamL_im);
  k_cast_x<<<dim3((TSEQ * DMOD / 4) / 256), dim3(256), 0, stream>>>(inputs, xb);
  k_make_bcat<<<dim3((HID * DMOD / 4) / 256), dim3(256), 0, stream>>>(B_re, B_im, gamma_log, Bcat);

  gemm8<false><<<dim3((TSEQ / 256) * (HID2 / 256)), dim3(512), 0, stream>>>(
      xb, Bcat, (void*)Bu, nullptr, nullptr);

  s_chunk_end<<<dim3(NCH * HID / 4 / 256), dim3(256), 0, stream>>>(Bu, lam_re, lam_im, E);
  s_prefix<<<dim3(HID / 256), dim3(256), 0, stream>>>(lamL_re, lamL_im, E, P);
  s_expand<<<dim3(NCH * HID / 4 / 256), dim3(256), 0, stream>>>(Bu, lam_re, lam_im, P, xb /*A2*/);

  k_make_ccat<<<dim3((DMOD * HID / 4) / 256), dim3(256), 0, stream>>>(C_re, C_im, Bcat /*Ccat*/);

  gemm8<true><<<dim3((TSEQ / 256) * (DMOD / 256)), dim3(512), 0, stream>>>(
      xb /*hidden*/, Bcat /*Ccat*/, (void*)out, inputs, Dvec);
}